// Round 4
// baseline (907.071 us; speedup 1.0000x reference)
//
#include <hip/hip_runtime.h>
#include <math.h>

#define IMG 768
#define TX 96
#define TY 24
#define KF 4
#define ITX (TX + 2 * KF)     // 104
#define ITY (TY + 2 * KF)     // 32
#define NBX (IMG / TX)        // 8
#define NBY (IMG / TY)        // 32 -> 256 blocks = exactly 1 per CU
#define NT 768                // 12 waves/block
#define QX ((ITX - 2) / 2)    // 51
#define QY ((ITY - 2) / 2)    // 15
#define NQ (QX * QY)          // 765 quads vs 768 threads: 99.6% util
#define RES_SCALE 0.1f
#define NITER 64

// Exact GELU: 0.5*x*(1+erf(x/sqrt(2))), erf via Abramowitz-Stegun 7.1.26
// (|abs err| < 1.5e-7 over full range), branchless, hw rcp + exp2.
__device__ __forceinline__ float gelu_exact(float x) {
    float t = fabsf(x) * 0.70710678118654752f;
    float kk = __builtin_amdgcn_rcpf(fmaf(0.3275911f, t, 1.0f));
    float p = fmaf(1.061405429f, kk, -1.453152027f);
    p = fmaf(p, kk, 1.421413741f);
    p = fmaf(p, kk, -0.284496736f);
    p = fmaf(p, kk, 0.254829592f);
    p *= kk;
    float e = __builtin_amdgcn_exp2f(-t * t * 1.4426950408889634f);
    float r = fmaf(-e, p, 1.0f);   // erf(|x|/sqrt2) in [0,1]
    float es = copysignf(r, x);
    return 0.5f * x * (1.0f + es);
}

__global__ void resize_bilinear(const float* __restrict__ seed, float* __restrict__ out) {
    int idx = blockIdx.x * blockDim.x + threadIdx.x;
    if (idx >= IMG * IMG) return;
    int i = idx / IMG, j = idx - i * IMG;
    // half-pixel centers, align_corners=False; edge renormalization == clamp
    float sy = (i + 0.5f) * (8.0f / 768.0f) - 0.5f;
    float sx = (j + 0.5f) * (8.0f / 768.0f) - 0.5f;
    float fy = floorf(sy), fx = floorf(sx);
    float wy = sy - fy, wx = sx - fx;
    int y0 = (int)fy, x0 = (int)fx;
    int y0c = min(max(y0, 0), 7), y1c = min(max(y0 + 1, 0), 7);
    int x0c = min(max(x0, 0), 7), x1c = min(max(x0 + 1, 0), 7);
    float v00 = seed[y0c * 8 + x0c], v01 = seed[y0c * 8 + x1c];
    float v10 = seed[y1c * 8 + x0c], v11 = seed[y1c * 8 + x1c];
    float top = v00 + wx * (v01 - v00);
    float bot = v10 + wx * (v11 - v10);
    out[idx] = top + wy * (bot - top);
}

// KF residual iterations fused per launch. 2x2 quad per thread with a fixed
// quad->LDS mapping (fixed compute bounds; shrinking-validity handled by
// induction: garbage rings are finite and never drained). 4x4 patch via
// ds_read_b64 pairs; per-channel wave-uniform GELU-saturation fast path.
__global__ __launch_bounds__(NT) void fused_steps(
        const float* __restrict__ xin, float* __restrict__ xout,
        const float* __restrict__ gw1, const float* __restrict__ gb1,
        const float* __restrict__ gw2, const float* __restrict__ gb2) {
    __shared__ float buf[2][ITY * ITX];   // 2 x 32x104 x 4B = 26.6 KB
    const int tid = threadIdx.x;
    const int bx = blockIdx.x % NBX, by = blockIdx.x / NBX;
    const int gx0 = bx * TX - KF, gy0 = by * TY - KF;
    const bool border = (bx == 0) | (bx == NBX - 1) | (by == 0) | (by == NBY - 1);

    // ---- stage 104x32 input tile (zeros outside image = 'SAME' zero pad) ----
    if (!border) {
        for (int t = tid; t < (ITX / 4) * ITY; t += NT) {   // 26*32 = 832 float4
            int r = t / (ITX / 4), c4 = t - r * (ITX / 4);
            float4 v = *reinterpret_cast<const float4*>(&xin[(gy0 + r) * IMG + gx0 + c4 * 4]);
            *reinterpret_cast<float4*>(&buf[0][r * ITX + c4 * 4]) = v;
        }
    } else {
        for (int t = tid; t < ITY * ITX; t += NT) {
            int r = t / ITX, c = t - r * ITX;
            int gy = gy0 + r, gx = gx0 + c;
            float v = 0.0f;
            if (gy >= 0 && gy < IMG && gx >= 0 && gx < IMG) v = xin[gy * IMG + gx];
            buf[0][t] = v;
        }
    }
    __syncthreads();

    // ---- fixed quad assignment (constant across all KF steps) ----
    const int q = min(tid, NQ - 1);          // 3 excess threads dup quad 764 (benign)
    const int qyi = q / QX, qxi = q - qyi * QX;
    const int R = 1 + 2 * qyi;               // output top row in LDS
    const int C = 1 + 2 * qxi;               // output left col in LDS
    const int pbase = (R - 1) * ITX + (C - 1);  // 4x4 patch origin (even,even) -> 8B aligned
    const int sbase = R * ITX + C;

    // ghost masks (pixels outside the image must stay exactly 0 every step)
    float m00 = 1.f, m01 = 1.f, m10 = 1.f, m11 = 1.f;
    if (border) {
        int gyA = gy0 + R, gyB = gyA + 1, gxA = gx0 + C, gxB = gxA + 1;
        bool ya = (gyA >= 0) & (gyA < IMG), yb = (gyB >= 0) & (gyB < IMG);
        bool xa = (gxA >= 0) & (gxA < IMG), xb = (gxB >= 0) & (gxB < IMG);
        m00 = (ya & xa) ? 1.f : 0.f;  m01 = (ya & xb) ? 1.f : 0.f;
        m10 = (yb & xa) ? 1.f : 0.f;  m11 = (yb & xb) ? 1.f : 0.f;
    }

    const float yinit = gb2[0] * RES_SCALE;

#pragma unroll 2
    for (int j = 0; j < KF; ++j) {
        const float* __restrict__ src = &buf[j & 1][0];
        float* __restrict__ dst = &buf[(j & 1) ^ 1][0];

        // load 4x4 patch: 8 x ds_read_b64 (8B-aligned), offsets compile-time
        float p[4][4];
#pragma unroll
        for (int r = 0; r < 4; ++r) {
            float2 a = *reinterpret_cast<const float2*>(&src[pbase + r * ITX]);
            float2 b = *reinterpret_cast<const float2*>(&src[pbase + r * ITX + 2]);
            p[r][0] = a.x; p[r][1] = a.y; p[r][2] = b.x; p[r][3] = b.y;
        }

        float y00 = yinit, y01 = yinit, y10 = yinit, y11 = yinit;
#pragma unroll
        for (int ch = 0; ch < 16; ++ch) {
            const float* wc = &gw1[ch * 9];       // uniform -> s_load
            const float bb = gb1[ch];
            const float ws = gw2[ch] * RES_SCALE;
            float a00 = bb, a01 = bb, a10 = bb, a11 = bb;
#pragma unroll
            for (int dy = 0; dy < 3; ++dy)
#pragma unroll
                for (int dx = 0; dx < 3; ++dx) {
                    float w = wc[dy * 3 + dx];
                    a00 = fmaf(w, p[dy][dx],         a00);
                    a01 = fmaf(w, p[dy][dx + 1],     a01);
                    a10 = fmaf(w, p[dy + 1][dx],     a10);
                    a11 = fmaf(w, p[dy + 1][dx + 1], a11);
                }
            // fp32 erf saturates exactly for |a|>5.66 -> relu path; one
            // wave-uniform branch per channel. min3 with free |.| modifiers.
            float mn = fminf(fminf(fabsf(a00), fabsf(a01)),
                             fminf(fabsf(a10), fabsf(a11)));
            if (__all(mn > 5.7f)) {
                y00 = fmaf(ws, fmaxf(a00, 0.f), y00);
                y01 = fmaf(ws, fmaxf(a01, 0.f), y01);
                y10 = fmaf(ws, fmaxf(a10, 0.f), y10);
                y11 = fmaf(ws, fmaxf(a11, 0.f), y11);
            } else {
                y00 = fmaf(ws, gelu_exact(a00), y00);
                y01 = fmaf(ws, gelu_exact(a01), y01);
                y10 = fmaf(ws, gelu_exact(a10), y10);
                y11 = fmaf(ws, gelu_exact(a11), y11);
            }
        }

        float v00 = p[1][1] + y00, v01 = p[1][2] + y01;
        float v10 = p[2][1] + y10, v11 = p[2][2] + y11;
        if (border) { v00 *= m00; v01 *= m01; v10 *= m10; v11 *= m11; }
        dst[sbase]           = v00;
        dst[sbase + 1]       = v01;
        dst[sbase + ITX]     = v10;
        dst[sbase + ITX + 1] = v11;
        __syncthreads();
    }

    // ---- drain inner 96x24 (always fully in-image; KF even -> buf[0]) ----
    for (int t = tid; t < (TX / 4) * TY; t += NT) {   // 24*24 = 576 float4
        int r = t / (TX / 4), c4 = t - r * (TX / 4);
        *reinterpret_cast<float4*>(&xout[(gy0 + KF + r) * IMG + gx0 + KF + c4 * 4]) =
            *reinterpret_cast<const float4*>(&buf[0][(KF + r) * ITX + KF + c4 * 4]);
    }
}

extern "C" void kernel_launch(void* const* d_in, const int* in_sizes, int n_in,
                              void* d_out, int out_size, void* d_ws, size_t ws_size,
                              hipStream_t stream) {
    const float* seed = (const float*)d_in[0];
    const float* w1   = (const float*)d_in[1];
    const float* b1   = (const float*)d_in[2];
    const float* w2   = (const float*)d_in[3];
    const float* b2   = (const float*)d_in[4];
    // d_in[5]/d_in[6] are rows/cols = 768/768 (fixed by setup_inputs)

    float* out = (float*)d_out;
    float* ws  = (float*)d_ws;   // second ping-pong buffer (2.36 MB)

    resize_bilinear<<<(IMG * IMG + 255) / 256, 256, 0, stream>>>(seed, out);

    float* a = out;
    float* b = ws;
    for (int it = 0; it < NITER; it += KF) {   // 16 launches, even -> ends in d_out
        fused_steps<<<NBX * NBY, NT, 0, stream>>>(a, b, w1, b1, w2, b2);
        float* t = a; a = b; b = t;
    }
}

// Round 5
// 721.375 us; speedup vs baseline: 1.2574x; 1.2574x over previous
//
#include <hip/hip_runtime.h>
#include <math.h>

#define IMG 768
#define TILE 24
#define KF 4
#define IT (TILE + 2 * KF)    // 32x32 input tile, power-of-2 row stride
#define NB (IMG / TILE)       // 32 -> 1024 blocks = 4 per CU
#define NT 256                // 4 waves/block
#define RES_SCALE 0.1f
#define NITER 64

// Exact GELU: 0.5*x*(1+erf(x/sqrt(2))), erf via Abramowitz-Stegun 7.1.26
// (|abs err| < 1.5e-7 over full range), branchless, hw rcp + exp2.
__device__ __forceinline__ float gelu_exact(float x) {
    float t = fabsf(x) * 0.70710678118654752f;
    float kk = __builtin_amdgcn_rcpf(fmaf(0.3275911f, t, 1.0f));
    float p = fmaf(1.061405429f, kk, -1.453152027f);
    p = fmaf(p, kk, 1.421413741f);
    p = fmaf(p, kk, -0.284496736f);
    p = fmaf(p, kk, 0.254829592f);
    p *= kk;
    float e = __builtin_amdgcn_exp2f(-t * t * 1.4426950408889634f);
    float r = fmaf(-e, p, 1.0f);   // erf(|x|/sqrt2) in [0,1]
    float es = copysignf(r, x);
    return 0.5f * x * (1.0f + es);
}

__global__ void resize_bilinear(const float* __restrict__ seed, float* __restrict__ out) {
    int idx = blockIdx.x * blockDim.x + threadIdx.x;
    if (idx >= IMG * IMG) return;
    int i = idx / IMG, j = idx - i * IMG;
    // half-pixel centers, align_corners=False; edge renormalization == clamp
    float sy = (i + 0.5f) * (8.0f / 768.0f) - 0.5f;
    float sx = (j + 0.5f) * (8.0f / 768.0f) - 0.5f;
    float fy = floorf(sy), fx = floorf(sx);
    float wy = sy - fy, wx = sx - fx;
    int y0 = (int)fy, x0 = (int)fx;
    int y0c = min(max(y0, 0), 7), y1c = min(max(y0 + 1, 0), 7);
    int x0c = min(max(x0, 0), 7), x1c = min(max(x0 + 1, 0), 7);
    float v00 = seed[y0c * 8 + x0c], v01 = seed[y0c * 8 + x1c];
    float v10 = seed[y1c * 8 + x0c], v11 = seed[y1c * 8 + x1c];
    float top = v00 + wx * (v01 - v00);
    float bot = v10 + wx * (v11 - v10);
    out[idx] = top + wy * (bot - top);
}

// KF residual iterations fused per launch; shrinking-halo LDS tiles.
// Channel-outer over a batch of B pixels per thread (B independent 9-FMA
// chains = ILP), weights amortized over B, one saturation branch per channel.
// R3 compute structure; geometry retuned for 4 blocks/CU latency hiding.
__global__ __launch_bounds__(NT, 4) void fused_steps(
        const float* __restrict__ xin, float* __restrict__ xout,
        const float* __restrict__ gw1, const float* __restrict__ gb1,
        const float* __restrict__ gw2, const float* __restrict__ gb2) {
    __shared__ float buf[2][IT * IT];   // 2 x 32x32 x 4B = 8 KB
    const int tid = threadIdx.x;
    const int bx = blockIdx.x % NB, by = blockIdx.x / NB;
    const int gx0 = bx * TILE - KF, gy0 = by * TILE - KF;
    const bool border = (bx == 0) | (bx == NB - 1) | (by == 0) | (by == NB - 1);

    // ---- stage 32x32 input tile (zeros outside image = 'SAME' zero pad) ----
    if (!border) {
        // exactly one float4 per thread: 256 x 16B = 4 KB
        int r = tid >> 3, c4 = tid & 7;
        *reinterpret_cast<float4*>(&buf[0][r * IT + c4 * 4]) =
            *reinterpret_cast<const float4*>(&xin[(gy0 + r) * IMG + gx0 + c4 * 4]);
    } else {
        for (int t = tid; t < IT * IT; t += NT) {
            int r = t >> 5, c = t & 31;
            int gy = gy0 + r, gx = gx0 + c;
            float v = 0.0f;
            if (gy >= 0 && gy < IMG && gx >= 0 && gx < IMG) v = xin[gy * IMG + gx];
            buf[0][t] = v;
        }
    }
    __syncthreads();

    const float yinit = gb2[0] * RES_SCALE;

#pragma unroll
    for (int j = 0; j < KF; ++j) {
        const int S = (IT - 2) - 2 * j;       // 30,28,26,24
        const int off = j + 1;
        const int total = S * S;              // 900,784,676,576
        const int B = (total + NT - 1) / NT;  // 4,4,3,3 (compile-time)
        const float* __restrict__ src = &buf[j & 1][0];
        float* __restrict__ dst = &buf[(j & 1) ^ 1][0];

        int rr[4], cc[4];
        bool ok[4];
        float nb[4][9];
#pragma unroll
        for (int k = 0; k < B; ++k) {
            int p = tid + k * NT;
            ok[k] = p < total;
            if (!ok[k]) p = total - 1;        // clamp: duplicate a valid pixel
            int q = p / S;                    // S compile-time -> magic mul
            rr[k] = off + q;
            cc[k] = off + (p - q * S);
            const float* s0 = &src[(rr[k] - 1) * IT + cc[k] - 1];
            nb[k][0] = s0[0];          nb[k][1] = s0[1];          nb[k][2] = s0[2];
            nb[k][3] = s0[IT];         nb[k][4] = s0[IT + 1];     nb[k][5] = s0[IT + 2];
            nb[k][6] = s0[2 * IT];     nb[k][7] = s0[2 * IT + 1]; nb[k][8] = s0[2 * IT + 2];
        }
        float y[4];
#pragma unroll
        for (int k = 0; k < B; ++k) y[k] = yinit;

#pragma unroll
        for (int ch = 0; ch < 16; ++ch) {
            const float* wc = &gw1[ch * 9];        // uniform -> s_load
            const float b1c = gb1[ch];
            const float w2c = gw2[ch] * RES_SCALE; // pre-scaled accumulate
            float a[4];
            float mn = 1e30f;
#pragma unroll
            for (int k = 0; k < B; ++k) {          // B independent FMA chains
                float t = b1c;
                t = fmaf(wc[0], nb[k][0], t);
                t = fmaf(wc[1], nb[k][1], t);
                t = fmaf(wc[2], nb[k][2], t);
                t = fmaf(wc[3], nb[k][3], t);
                t = fmaf(wc[4], nb[k][4], t);
                t = fmaf(wc[5], nb[k][5], t);
                t = fmaf(wc[6], nb[k][6], t);
                t = fmaf(wc[7], nb[k][7], t);
                t = fmaf(wc[8], nb[k][8], t);
                a[k] = t;
                mn = fminf(mn, fabsf(t));
            }
            // fp32 erf saturates exactly for |a|>5.66 -> relu path, one
            // wave-uniform branch per channel per batch
            if (__all(mn > 5.7f)) {
#pragma unroll
                for (int k = 0; k < B; ++k)
                    y[k] = fmaf(w2c, fmaxf(a[k], 0.0f), y[k]);
            } else {
#pragma unroll
                for (int k = 0; k < B; ++k)
                    y[k] = fmaf(w2c, gelu_exact(a[k]), y[k]);
            }
        }

#pragma unroll
        for (int k = 0; k < B; ++k) {
            float v = nb[k][4] + y[k];
            if (border) {
                int gy = gy0 + rr[k], gx = gx0 + cc[k];
                bool inimg = (gy >= 0) & (gy < IMG) & (gx >= 0) & (gx < IMG);
                // ghost pixels outside image stay 0 every iteration (zero pad)
                if (!inimg) v = 0.0f;
            }
            if (ok[k]) dst[rr[k] * IT + cc[k]] = v;
        }
        __syncthreads();
    }

    // ---- drain inner 24x24 (always fully in-image; KF even -> buf[0]) ----
    {
        int t = tid;                      // 24*6 = 144 float4 over 256 threads
        if (t < (TILE / 4) * TILE) {
            int r = t / (TILE / 4), c4 = t - r * (TILE / 4);
            *reinterpret_cast<float4*>(&xout[(gy0 + KF + r) * IMG + gx0 + KF + c4 * 4]) =
                *reinterpret_cast<const float4*>(&buf[0][(KF + r) * IT + KF + c4 * 4]);
        }
    }
}

extern "C" void kernel_launch(void* const* d_in, const int* in_sizes, int n_in,
                              void* d_out, int out_size, void* d_ws, size_t ws_size,
                              hipStream_t stream) {
    const float* seed = (const float*)d_in[0];
    const float* w1   = (const float*)d_in[1];
    const float* b1   = (const float*)d_in[2];
    const float* w2   = (const float*)d_in[3];
    const float* b2   = (const float*)d_in[4];
    // d_in[5]/d_in[6] are rows/cols = 768/768 (fixed by setup_inputs)

    float* out = (float*)d_out;
    float* ws  = (float*)d_ws;   // second ping-pong buffer (2.36 MB)

    resize_bilinear<<<(IMG * IMG + 255) / 256, 256, 0, stream>>>(seed, out);

    float* a = out;
    float* b = ws;
    for (int it = 0; it < NITER; it += KF) {   // 16 launches, even -> ends in d_out
        fused_steps<<<NB * NB, NT, 0, stream>>>(a, b, w1, b1, w2, b2);
        float* t = a; a = b; b = t;
    }
}